// Round 5
// baseline (427.492 us; speedup 1.0000x reference)
//
#include <hip/hip_runtime.h>
#include <stdint.h>

#define M_ROWS 16384   // B*S
#define N_COLS 4096    // OUT
#define K_DIM  1024    // IN
#define NTILES 32      // 4 groups x 8 K-tiles (BK=128 int8), persistent pipeline

typedef int i32x4 __attribute__((ext_vector_type(4)));

// ---- async global->LDS, 16B per lane, LDS dest is wave-uniform base + lane*16
__device__ __forceinline__ void gload_lds16(const void* g, void* l) {
    __builtin_amdgcn_global_load_lds(
        (const __attribute__((address_space(1))) unsigned int*)g,
        (__attribute__((address_space(3))) unsigned int*)l, 16, 0, 0);
}

// raw barrier pinned against compiler motion
#define SBAR() do { __builtin_amdgcn_sched_barrier(0); \
                    __builtin_amdgcn_s_barrier();      \
                    __builtin_amdgcn_sched_barrier(0); } while (0)

// ---------------- kernel 1: per-block min/max of x ----------------
__global__ void k_minmax(const float4* __restrict__ x,
                         float* __restrict__ pmax, float* __restrict__ pmin) {
    const int n4 = (M_ROWS * K_DIM) / 4;
    float mx = -3.402823466e38f, mn = 3.402823466e38f;
    for (int i = blockIdx.x * blockDim.x + threadIdx.x; i < n4;
         i += gridDim.x * blockDim.x) {
        float4 v = x[i];
        mx = fmaxf(mx, fmaxf(fmaxf(v.x, v.y), fmaxf(v.z, v.w)));
        mn = fminf(mn, fminf(fminf(v.x, v.y), fminf(v.z, v.w)));
    }
#pragma unroll
    for (int off = 32; off > 0; off >>= 1) {
        mx = fmaxf(mx, __shfl_xor(mx, off));
        mn = fminf(mn, __shfl_xor(mn, off));
    }
    __shared__ float smx[4], smn[4];
    const int wave = threadIdx.x >> 6, lane = threadIdx.x & 63;
    if (lane == 0) { smx[wave] = mx; smn[wave] = mn; }
    __syncthreads();
    if (threadIdx.x == 0) {
        mx = fmaxf(fmaxf(smx[0], smx[1]), fmaxf(smx[2], smx[3]));
        mn = fminf(fminf(smn[0], smn[1]), fminf(smn[2], smn[3]));
        pmax[blockIdx.x] = mx;
        pmin[blockIdx.x] = mn;
    }
}

// ---------------- kernel 2: final scalars (scale, zp, alpha) ----------------
__global__ void k_scalars(const float* __restrict__ pmax, const float* __restrict__ pmin,
                          const float* __restrict__ w_scale, float* __restrict__ scal) {
    float mx = -3.402823466e38f, mn = 3.402823466e38f;
    for (int i = threadIdx.x; i < 2048; i += 256) {
        mx = fmaxf(mx, pmax[i]);
        mn = fminf(mn, pmin[i]);
    }
#pragma unroll
    for (int off = 32; off > 0; off >>= 1) {
        mx = fmaxf(mx, __shfl_xor(mx, off));
        mn = fminf(mn, __shfl_xor(mn, off));
    }
    __shared__ float smx[4], smn[4];
    const int wave = threadIdx.x >> 6, lane = threadIdx.x & 63;
    if (lane == 0) { smx[wave] = mx; smn[wave] = mn; }
    __syncthreads();
    if (threadIdx.x == 0) {
        mx = fmaxf(fmaxf(smx[0], smx[1]), fmaxf(smx[2], smx[3]));
        mn = fminf(fminf(smn[0], smn[1]), fminf(smn[2], smn[3]));
        const float scale = (mx - mn) / 255.0f;
        const float zp = rintf((mx * -128.0f - mn * 127.0f) / (mx - mn));
        scal[0] = scale;
        scal[1] = zp;
        scal[2] = scale * w_scale[0];
    }
}

// ------- kernel 3: quantize x -> int8 + row term cma[m] = zw*(K*zx - sx[m])*alpha
__global__ void k_quant(const float* __restrict__ x, const float* __restrict__ scal,
                        const float* __restrict__ wzp,
                        int4* __restrict__ xc8, float* __restrict__ cma) {
    const float scale = scal[0], zx = scal[1], zw = wzp[0], alpha = scal[2];
    const int lane = threadIdx.x & 63;
    const int gw = (blockIdx.x * blockDim.x + threadIdx.x) >> 6;
    const int nw = (gridDim.x * blockDim.x) >> 6;
    for (int row = gw; row < M_ROWS; row += nw) {
        const float4* xr = (const float4*)(x + (size_t)row * K_DIM + lane * 16);
        union { signed char c[16]; int4 v; } u;
        int s = 0;
#pragma unroll
        for (int e = 0; e < 4; ++e) {
            float4 v = xr[e];
            signed char c0 = (signed char)(int)(rintf(v.x / scale) + zx);
            signed char c1 = (signed char)(int)(rintf(v.y / scale) + zx);
            signed char c2 = (signed char)(int)(rintf(v.z / scale) + zx);
            signed char c3 = (signed char)(int)(rintf(v.w / scale) + zx);
            u.c[e * 4 + 0] = c0; u.c[e * 4 + 1] = c1;
            u.c[e * 4 + 2] = c2; u.c[e * 4 + 3] = c3;
            s += (int)c0 + (int)c1 + (int)c2 + (int)c3;
        }
        xc8[row * 64 + lane] = u.v;
#pragma unroll
        for (int off = 32; off > 0; off >>= 1) s += __shfl_xor(s, off);
        if (lane == 0) cma[row] = zw * (1024.0f * zx - (float)s) * alpha;
    }
}

// ------- kernel 4: pack weights -> int8 + col term cnb[o] = -zx*sw[o]*alpha + bias[o]
__global__ void k_prepw(const int* __restrict__ wq, const float* __restrict__ scal,
                        const float* __restrict__ bias,
                        int4* __restrict__ wc8, float* __restrict__ cnb) {
    const float zx = scal[1], alpha = scal[2];
    const int lane = threadIdx.x & 63;
    const int gw = (blockIdx.x * blockDim.x + threadIdx.x) >> 6;
    const int nw = (gridDim.x * blockDim.x) >> 6;
    for (int row = gw; row < N_COLS; row += nw) {
        const int4* wr = (const int4*)(wq + (size_t)row * K_DIM + lane * 16);
        union { signed char c[16]; int4 v; } u;
        int s = 0;
#pragma unroll
        for (int e = 0; e < 4; ++e) {
            int4 v = wr[e];
            u.c[e * 4 + 0] = (signed char)v.x;
            u.c[e * 4 + 1] = (signed char)v.y;
            u.c[e * 4 + 2] = (signed char)v.z;
            u.c[e * 4 + 3] = (signed char)v.w;
            s += v.x + v.y + v.z + v.w;
        }
        wc8[row * 64 + lane] = u.v;
#pragma unroll
        for (int off = 32; off > 0; off >>= 1) s += __shfl_xor(s, off);
        if (lane == 0) cnb[row] = -zx * (float)s * alpha + bias[row];
    }
}

// ---------------- kernel 5: persistent 256x256x128 8-phase int8 GEMM ----------
// 256 blocks (1/CU), each: fixed bm-panel, 4 bn-groups, tiles u=0..31 in ONE
// continuous pipeline (A(u+1) staged @q0,q1; B(u+2) @q2,q3; gate vmcnt(4)).
// Group epilogue stores are fire-and-forget: drained at the next group's first
// gate, overlapped with MFMA phases. XCD-exact tiling: bm=(b&7)*8+(b>>5) keeps
// each A-panel on one XCD (A fetched ~once from HBM).
// out[m,o] = (float)i32dot * alpha + cma[m] + cnb[o]
__global__ __launch_bounds__(512, 2)
void k_gemm(const signed char* __restrict__ A,
            const signed char* __restrict__ B,
            const float* __restrict__ scal,
            const float* __restrict__ cma,
            const float* __restrict__ cnb,
            float* __restrict__ C) {
    __shared__ char lds[131072];  // A: buf b at b*32768 ; B: 65536 + b*32768

    const int tid  = threadIdx.x;
    const int wave = tid >> 6, lane = tid & 63;
    const int wm = wave >> 2, wn = wave & 3;     // 2 x 4 wave grid
    const int fr = lane & 15, kg = lane >> 4;

    const int blk   = blockIdx.x;        // 0..255, XCD = blk & 7
    const int bm    = (blk & 7) * 8 + (blk >> 5);   // 0..63, XCD-exclusive panels
    const int bngrp = (blk >> 3) & 3;               // group g -> bn = bngrp*4 + g

    // staging lane geometry (pre-swizzled global source): phys = logical ^ ((row&7)<<4)
    const int scol = ((tid & 7) ^ ((tid >> 3) & 7)) << 4;
    const int srow = tid >> 3;           // 0..63
    const char* gA  = (const char*)A + (size_t)(bm * 256 + srow) * K_DIM + scol;
    const char* gB0 = (const char*)B + (size_t)(bngrp * 4 * 256 + srow) * K_DIM + scol;

    // tile u: A content depends on u&7 only (same bm all groups); B adds group row-off
#define STAGE_A(u, h) do {                                                    \
        const char* g_ = gA + (size_t)((u) & 7) * 128 + (size_t)(h) * 131072; \
        char* l_ = lds + ((u) & 1) * 32768 + (h) * 16384 + wave * 1024;       \
        gload_lds16(g_, l_);                                                  \
        gload_lds16(g_ + 65536, l_ + 8192);                                   \
    } while (0)
#define STAGE_B(u, h) do {                                                    \
        const char* g_ = gB0 + (size_t)((u) >> 3) * 262144                    \
                             + (size_t)((u) & 7) * 128 + (size_t)(h) * 131072; \
        char* l_ = lds + 65536 + ((u) & 1) * 32768 + (h) * 16384 + wave * 1024; \
        gload_lds16(g_, l_);                                                  \
        gload_lds16(g_ + 65536, l_ + 8192);                                   \
    } while (0)

    // fragment-read constants (swizzled); kk selects 64-byte K-half
    const int kx0 = ((kg * 16) ^ ((fr & 7) << 4));
    const int kx1 = ((64 + kg * 16) ^ ((fr & 7) << 4));
    const int arow = (wm * 128 + fr) * 128;
    const int brow = (wn * 64 + fr) * 128;

    const float alpha = scal[2];

    i32x4 acc[8][4] = {};
    i32x4 bf[4][2];

    // ---- prologue (once per kernel): tile0 + B(1); vmcnt(4) -> tile0 landed
    STAGE_A(0, 0); STAGE_A(0, 1);
    STAGE_B(0, 0); STAGE_B(0, 1);
    STAGE_B(1, 0); STAGE_B(1, 1);
    asm volatile("s_waitcnt vmcnt(4)" ::: "memory");
    SBAR();

    for (int u = 0; u < NTILES; ++u) {
        const int b = u & 1;
        const char* Ab = lds + b * 32768;
        const char* Bb = lds + 65536 + b * 32768;
#pragma unroll
        for (int q = 0; q < 4; ++q) {
            i32x4 af[2][2];
            if (q == 0) {
#pragma unroll
                for (int j = 0; j < 4; ++j) {
                    bf[j][0] = *(const i32x4*)(Bb + brow + j * 2048 + kx0);
                    bf[j][1] = *(const i32x4*)(Bb + brow + j * 2048 + kx1);
                }
            }
#pragma unroll
            for (int i2 = 0; i2 < 2; ++i2) {
                const int i = 2 * q + i2;
                af[i2][0] = *(const i32x4*)(Ab + arow + i * 2048 + kx0);
                af[i2][1] = *(const i32x4*)(Ab + arow + i * 2048 + kx1);
            }
            if (q == 0)      { if (u + 1 < NTILES) STAGE_A(u + 1, 0); }
            else if (q == 1) { if (u + 1 < NTILES) STAGE_A(u + 1, 1); }
            else if (q == 2) { if (u + 2 < NTILES) STAGE_B(u + 2, 0); }
            else {
                if (u + 2 < NTILES) {
                    STAGE_B(u + 2, 1);
                    asm volatile("s_waitcnt vmcnt(4)" ::: "memory");
                } else {
                    asm volatile("s_waitcnt vmcnt(0)" ::: "memory");
                }
            }
            SBAR();
            __builtin_amdgcn_s_setprio(1);
#pragma unroll
            for (int kk = 0; kk < 2; ++kk)
#pragma unroll
                for (int i2 = 0; i2 < 2; ++i2)
#pragma unroll
                    for (int j = 0; j < 4; ++j)
                        acc[2 * q + i2][j] = __builtin_amdgcn_mfma_i32_16x16x64_i8(
                            af[i2][kk], bf[j][kk], acc[2 * q + i2][j], 0, 0, 0);
            __builtin_amdgcn_s_setprio(0);
            SBAR();
        }

        // ---- group epilogue: stores fire-and-forget, drained at next group's gate
        if ((u & 7) == 7) {
            const int g = u >> 3;
            const int gc_base = (bngrp * 4 + g) * 256 + wn * 64;
            const int gr_base = bm * 256 + wm * 128;
            float cc[4];
#pragma unroll
            for (int j = 0; j < 4; ++j) cc[j] = cnb[gc_base + j * 16 + fr];
#pragma unroll
            for (int i = 0; i < 8; ++i) {
                const int gr0 = gr_base + i * 16 + kg * 4;
                const float4 cmv = *(const float4*)(cma + gr0);
#pragma unroll
                for (int j = 0; j < 4; ++j) {
                    const int gc = gc_base + j * 16 + fr;
                    C[(size_t)(gr0 + 0) * N_COLS + gc] = (float)acc[i][j][0] * alpha + (cmv.x + cc[j]);
                    C[(size_t)(gr0 + 1) * N_COLS + gc] = (float)acc[i][j][1] * alpha + (cmv.y + cc[j]);
                    C[(size_t)(gr0 + 2) * N_COLS + gc] = (float)acc[i][j][2] * alpha + (cmv.z + cc[j]);
                    C[(size_t)(gr0 + 3) * N_COLS + gc] = (float)acc[i][j][3] * alpha + (cmv.w + cc[j]);
                }
            }
#pragma unroll
            for (int i = 0; i < 8; ++i)
#pragma unroll
                for (int j = 0; j < 4; ++j)
                    acc[i][j] = (i32x4){0, 0, 0, 0};
        }
    }
#undef STAGE_A
#undef STAGE_B
}

extern "C" void kernel_launch(void* const* d_in, const int* in_sizes, int n_in,
                              void* d_out, int out_size, void* d_ws, size_t ws_size,
                              hipStream_t stream) {
    const float* x    = (const float*)d_in[0];   // [8,2048,1024] f32
    const int*   wq   = (const int*)d_in[1];     // [4096,1024] int32 (int8 values)
    const float* wsc  = (const float*)d_in[2];   // scalar
    const float* wzp  = (const float*)d_in[3];   // scalar
    const float* bias = (const float*)d_in[4];   // [4096]
    float* out = (float*)d_out;                  // [8,2048,4096] f32

    char* ws = (char*)d_ws;
    int4*  xc8  = (int4*)(ws);                   // 16,777,216 B
    int4*  wc8  = (int4*)(ws + 16777216);        //  4,194,304 B
    float* cma  = (float*)(ws + 20971520);       //  65,536 B
    float* cnb  = (float*)(ws + 21037056);       //  16,384 B
    float* pmax = (float*)(ws + 21053440);
    float* pmin = (float*)(ws + 21061632);
    float* scal = (float*)(ws + 21069824);

    k_minmax <<<2048, 256, 0, stream>>>((const float4*)x, pmax, pmin);
    k_scalars<<<1,    256, 0, stream>>>(pmax, pmin, wsc, scal);
    k_prepw  <<<1024, 256, 0, stream>>>(wq, scal, bias, wc8, cnb);
    k_quant  <<<2048, 256, 0, stream>>>(x, scal, wzp, xc8, cma);
    k_gemm   <<<256,  512, 0, stream>>>((const signed char*)xc8, (const signed char*)wc8,
                                        scal, cma, cnb, out);
}

// Round 6
// 406.777 us; speedup vs baseline: 1.0509x; 1.0509x over previous
//
#include <hip/hip_runtime.h>
#include <stdint.h>

#define M_ROWS 16384   // B*S
#define N_COLS 4096    // OUT
#define K_DIM  1024    // IN
#define NT     (K_DIM / 128)   // 8 K-tiles of BK=128 (int8)

typedef int i32x4 __attribute__((ext_vector_type(4)));

// ---- async global->LDS, 16B per lane, LDS dest is wave-uniform base + lane*16
__device__ __forceinline__ void gload_lds16(const void* g, void* l) {
    __builtin_amdgcn_global_load_lds(
        (const __attribute__((address_space(1))) unsigned int*)g,
        (__attribute__((address_space(3))) unsigned int*)l, 16, 0, 0);
}

// raw barrier pinned against compiler motion
#define SBAR() do { __builtin_amdgcn_sched_barrier(0); \
                    __builtin_amdgcn_s_barrier();      \
                    __builtin_amdgcn_sched_barrier(0); } while (0)

// ---------------- kernel 1: per-block min/max of x ----------------
__global__ void k_minmax(const float4* __restrict__ x,
                         float* __restrict__ pmax, float* __restrict__ pmin) {
    const int n4 = (M_ROWS * K_DIM) / 4;
    float mx = -3.402823466e38f, mn = 3.402823466e38f;
    for (int i = blockIdx.x * blockDim.x + threadIdx.x; i < n4;
         i += gridDim.x * blockDim.x) {
        float4 v = x[i];
        mx = fmaxf(mx, fmaxf(fmaxf(v.x, v.y), fmaxf(v.z, v.w)));
        mn = fminf(mn, fminf(fminf(v.x, v.y), fminf(v.z, v.w)));
    }
#pragma unroll
    for (int off = 32; off > 0; off >>= 1) {
        mx = fmaxf(mx, __shfl_xor(mx, off));
        mn = fminf(mn, __shfl_xor(mn, off));
    }
    __shared__ float smx[4], smn[4];
    const int wave = threadIdx.x >> 6, lane = threadIdx.x & 63;
    if (lane == 0) { smx[wave] = mx; smn[wave] = mn; }
    __syncthreads();
    if (threadIdx.x == 0) {
        mx = fmaxf(fmaxf(smx[0], smx[1]), fmaxf(smx[2], smx[3]));
        mn = fminf(fminf(smn[0], smn[1]), fminf(smn[2], smn[3]));
        pmax[blockIdx.x] = mx;
        pmin[blockIdx.x] = mn;
    }
}

// ---------------- kernel 2: final scalars (scale, zp, alpha) ----------------
__global__ void k_scalars(const float* __restrict__ pmax, const float* __restrict__ pmin,
                          const float* __restrict__ w_scale, float* __restrict__ scal) {
    float mx = -3.402823466e38f, mn = 3.402823466e38f;
    for (int i = threadIdx.x; i < 2048; i += 256) {
        mx = fmaxf(mx, pmax[i]);
        mn = fminf(mn, pmin[i]);
    }
#pragma unroll
    for (int off = 32; off > 0; off >>= 1) {
        mx = fmaxf(mx, __shfl_xor(mx, off));
        mn = fminf(mn, __shfl_xor(mn, off));
    }
    __shared__ float smx[4], smn[4];
    const int wave = threadIdx.x >> 6, lane = threadIdx.x & 63;
    if (lane == 0) { smx[wave] = mx; smn[wave] = mn; }
    __syncthreads();
    if (threadIdx.x == 0) {
        mx = fmaxf(fmaxf(smx[0], smx[1]), fmaxf(smx[2], smx[3]));
        mn = fminf(fminf(smn[0], smn[1]), fminf(smn[2], smn[3]));
        const float scale = (mx - mn) / 255.0f;
        const float zp = rintf((mx * -128.0f - mn * 127.0f) / (mx - mn));
        scal[0] = scale;
        scal[1] = zp;
        scal[2] = scale * w_scale[0];
    }
}

// ------- kernel 3: quantize x -> int8 + row term cma[m] = zw*(K*zx - sx[m])*alpha
__global__ void k_quant(const float* __restrict__ x, const float* __restrict__ scal,
                        const float* __restrict__ wzp,
                        int4* __restrict__ xc8, float* __restrict__ cma) {
    const float scale = scal[0], zx = scal[1], zw = wzp[0], alpha = scal[2];
    const int lane = threadIdx.x & 63;
    const int gw = (blockIdx.x * blockDim.x + threadIdx.x) >> 6;
    const int nw = (gridDim.x * blockDim.x) >> 6;
    for (int row = gw; row < M_ROWS; row += nw) {
        const float4* xr = (const float4*)(x + (size_t)row * K_DIM + lane * 16);
        union { signed char c[16]; int4 v; } u;
        int s = 0;
#pragma unroll
        for (int e = 0; e < 4; ++e) {
            float4 v = xr[e];
            signed char c0 = (signed char)(int)(rintf(v.x / scale) + zx);
            signed char c1 = (signed char)(int)(rintf(v.y / scale) + zx);
            signed char c2 = (signed char)(int)(rintf(v.z / scale) + zx);
            signed char c3 = (signed char)(int)(rintf(v.w / scale) + zx);
            u.c[e * 4 + 0] = c0; u.c[e * 4 + 1] = c1;
            u.c[e * 4 + 2] = c2; u.c[e * 4 + 3] = c3;
            s += (int)c0 + (int)c1 + (int)c2 + (int)c3;
        }
        xc8[row * 64 + lane] = u.v;
#pragma unroll
        for (int off = 32; off > 0; off >>= 1) s += __shfl_xor(s, off);
        if (lane == 0) cma[row] = zw * (1024.0f * zx - (float)s) * alpha;
    }
}

// ------- kernel 4: pack weights -> int8 + col term cnb[o] = -zx*sw[o]*alpha + bias[o]
__global__ void k_prepw(const int* __restrict__ wq, const float* __restrict__ scal,
                        const float* __restrict__ bias,
                        int4* __restrict__ wc8, float* __restrict__ cnb) {
    const float zx = scal[1], alpha = scal[2];
    const int lane = threadIdx.x & 63;
    const int gw = (blockIdx.x * blockDim.x + threadIdx.x) >> 6;
    const int nw = (gridDim.x * blockDim.x) >> 6;
    for (int row = gw; row < N_COLS; row += nw) {
        const int4* wr = (const int4*)(wq + (size_t)row * K_DIM + lane * 16);
        union { signed char c[16]; int4 v; } u;
        int s = 0;
#pragma unroll
        for (int e = 0; e < 4; ++e) {
            int4 v = wr[e];
            u.c[e * 4 + 0] = (signed char)v.x;
            u.c[e * 4 + 1] = (signed char)v.y;
            u.c[e * 4 + 2] = (signed char)v.z;
            u.c[e * 4 + 3] = (signed char)v.w;
            s += v.x + v.y + v.z + v.w;
        }
        wc8[row * 64 + lane] = u.v;
#pragma unroll
        for (int off = 32; off > 0; off >>= 1) s += __shfl_xor(s, off);
        if (lane == 0) cnb[row] = -zx * (float)s * alpha + bias[row];
    }
}

// ---------------- kernel 5: 256x256x128 8-phase int8 GEMM (R3 base + NT stores)
// out[m,o] = (float)i32dot(x_q[m,:],w_q[o,:]) * alpha + cma[m] + cnb[o]
// Grid 1024, 2 blocks/CU resident (m114 overlap). Epilogue C-stores are
// NON-TEMPORAL: C is write-once/never-re-read; bypassing L2 retention keeps
// the per-XCD 4MB L2 holding A/B panels instead of dead write data.
__global__ __launch_bounds__(512, 2)
void k_gemm(const signed char* __restrict__ A,
            const signed char* __restrict__ B,
            const float* __restrict__ scal,
            const float* __restrict__ cma,
            const float* __restrict__ cnb,
            float* __restrict__ C) {
    __shared__ char lds[131072];  // A: buf b at b*32768 ; B: 65536 + b*32768

    const int tid  = threadIdx.x;
    const int wave = tid >> 6, lane = tid & 63;
    const int wm = wave >> 2, wn = wave & 3;
    const int fr = lane & 15, kg = lane >> 4;

    // XCD-aware bijective swizzle: nwg = 1024 = 8 * 128; all 16 bn-blocks of a
    // given bm land on the same XCD consecutively (A-panel L2 locality).
    const int wg  = blockIdx.x;
    const int swz = ((wg & 7) << 7) | (wg >> 3);
    const int bm  = swz >> 4;    // 0..63
    const int bn  = swz & 15;    // 0..15

    // staging lane geometry (pre-swizzled global source): phys = logical ^ ((row&7)<<4)
    const int scol = ((tid & 7) ^ ((tid >> 3) & 7)) << 4;
    const char* gA = (const char*)A + (size_t)(bm * 256 + (tid >> 3)) * K_DIM + scol;
    const char* gB = (const char*)B + (size_t)(bn * 256 + (tid >> 3)) * K_DIM + scol;

#define STAGE_A(tt, h, b) do {                                           \
        const char* g_ = gA + (size_t)(tt) * 128 + (size_t)(h) * 131072; \
        char* l_ = lds + (b) * 32768 + (h) * 16384 + wave * 1024;        \
        gload_lds16(g_, l_);                                             \
        gload_lds16(g_ + 65536, l_ + 8192);                              \
    } while (0)
#define STAGE_B(tt, h, b) do {                                           \
        const char* g_ = gB + (size_t)(tt) * 128 + (size_t)(h) * 131072; \
        char* l_ = lds + 65536 + (b) * 32768 + (h) * 16384 + wave * 1024; \
        gload_lds16(g_, l_);                                             \
        gload_lds16(g_ + 65536, l_ + 8192);                              \
    } while (0)

    // fragment-read constants (swizzled); kk selects 64-byte K-half
    const int kx0 = ((kg * 16) ^ ((fr & 7) << 4));
    const int kx1 = ((64 + kg * 16) ^ ((fr & 7) << 4));
    const int arow = (wm * 128 + fr) * 128;
    const int brow = (wn * 64 + fr) * 128;

    i32x4 acc[8][4] = {};
    i32x4 bf[4][2];

    // prologue: tile0 (8 calls) + B(1) (4 calls); vmcnt(4) -> tile0 landed
    STAGE_A(0, 0, 0); STAGE_A(0, 1, 0);
    STAGE_B(0, 0, 0); STAGE_B(0, 1, 0);
    STAGE_B(1, 0, 1); STAGE_B(1, 1, 1);
    asm volatile("s_waitcnt vmcnt(4)" ::: "memory");
    SBAR();

    for (int t = 0; t < NT; ++t) {
        const int b = t & 1;
        const char* Ab = lds + b * 32768;
        const char* Bb = lds + 65536 + b * 32768;
#pragma unroll
        for (int q = 0; q < 4; ++q) {
            i32x4 af[2][2];
            if (q == 0) {
#pragma unroll
                for (int j = 0; j < 4; ++j) {
                    bf[j][0] = *(const i32x4*)(Bb + brow + j * 2048 + kx0);
                    bf[j][1] = *(const i32x4*)(Bb + brow + j * 2048 + kx1);
                }
            }
#pragma unroll
            for (int i2 = 0; i2 < 2; ++i2) {
                const int i = 2 * q + i2;
                af[i2][0] = *(const i32x4*)(Ab + arow + i * 2048 + kx0);
                af[i2][1] = *(const i32x4*)(Ab + arow + i * 2048 + kx1);
            }
            if (q == 0)      { if (t + 1 < NT) STAGE_A(t + 1, 0, b ^ 1); }
            else if (q == 1) { if (t + 1 < NT) STAGE_A(t + 1, 1, b ^ 1); }
            else if (q == 2) { if (t + 2 < NT) STAGE_B(t + 2, 0, b); }
            else {
                if (t + 2 < NT) {
                    STAGE_B(t + 2, 1, b);
                    asm volatile("s_waitcnt vmcnt(4)" ::: "memory");
                } else {
                    asm volatile("s_waitcnt vmcnt(0)" ::: "memory");
                }
            }
            SBAR();
            __builtin_amdgcn_s_setprio(1);
#pragma unroll
            for (int kk = 0; kk < 2; ++kk)
#pragma unroll
                for (int i2 = 0; i2 < 2; ++i2)
#pragma unroll
                    for (int j = 0; j < 4; ++j)
                        acc[2 * q + i2][j] = __builtin_amdgcn_mfma_i32_16x16x64_i8(
                            af[i2][kk], bf[j][kk], acc[2 * q + i2][j], 0, 0, 0);
            __builtin_amdgcn_s_setprio(0);
            SBAR();
        }
    }

    // epilogue: C/D layout col=lane&15, row=(lane>>4)*4+r; NON-TEMPORAL stores
    const float alpha = scal[2];
    const int gc_base = bn * 256 + wn * 64;
    const int gr_base = bm * 256 + wm * 128;
    float cc[4];
#pragma unroll
    for (int j = 0; j < 4; ++j) cc[j] = cnb[gc_base + j * 16 + fr];
#pragma unroll
    for (int i = 0; i < 8; ++i) {
        const int gr0 = gr_base + i * 16 + kg * 4;
        const float4 cmv = *(const float4*)(cma + gr0);
#pragma unroll
        for (int j = 0; j < 4; ++j) {
            const int gc = gc_base + j * 16 + fr;
            __builtin_nontemporal_store((float)acc[i][j][0] * alpha + (cmv.x + cc[j]),
                                        &C[(size_t)(gr0 + 0) * N_COLS + gc]);
            __builtin_nontemporal_store((float)acc[i][j][1] * alpha + (cmv.y + cc[j]),
                                        &C[(size_t)(gr0 + 1) * N_COLS + gc]);
            __builtin_nontemporal_store((float)acc[i][j][2] * alpha + (cmv.z + cc[j]),
                                        &C[(size_t)(gr0 + 2) * N_COLS + gc]);
            __builtin_nontemporal_store((float)acc[i][j][3] * alpha + (cmv.w + cc[j]),
                                        &C[(size_t)(gr0 + 3) * N_COLS + gc]);
        }
    }
#undef STAGE_A
#undef STAGE_B
}

extern "C" void kernel_launch(void* const* d_in, const int* in_sizes, int n_in,
                              void* d_out, int out_size, void* d_ws, size_t ws_size,
                              hipStream_t stream) {
    const float* x    = (const float*)d_in[0];   // [8,2048,1024] f32
    const int*   wq   = (const int*)d_in[1];     // [4096,1024] int32 (int8 values)
    const float* wsc  = (const float*)d_in[2];   // scalar
    const float* wzp  = (const float*)d_in[3];   // scalar
    const float* bias = (const float*)d_in[4];   // [4096]
    float* out = (float*)d_out;                  // [8,2048,4096] f32

    char* ws = (char*)d_ws;
    int4*  xc8  = (int4*)(ws);                   // 16,777,216 B
    int4*  wc8  = (int4*)(ws + 16777216);        //  4,194,304 B
    float* cma  = (float*)(ws + 20971520);       //  65,536 B
    float* cnb  = (float*)(ws + 21037056);       //  16,384 B
    float* pmax = (float*)(ws + 21053440);
    float* pmin = (float*)(ws + 21061632);
    float* scal = (float*)(ws + 21069824);

    k_minmax <<<2048, 256, 0, stream>>>((const float4*)x, pmax, pmin);
    k_scalars<<<1,    256, 0, stream>>>(pmax, pmin, wsc, scal);
    k_prepw  <<<1024, 256, 0, stream>>>(wq, scal, bias, wc8, cnb);
    k_quant  <<<2048, 256, 0, stream>>>(x, scal, wzp, xc8, cma);
    k_gemm   <<<1024, 512, 0, stream>>>((const signed char*)xc8, (const signed char*)wc8,
                                        scal, cma, cnb, out);
}